// Round 2
// baseline (196.839 us; speedup 1.0000x reference)
//
#include <hip/hip_runtime.h>
#include <math.h>

#define N_ 16
#define C_ 4
#define F_ 257
#define T_ 1000
#define B_ 8
#define K_ 80
#define BK_ (B_*K_)   // 640
#define TT_ 128       // t-tile
// grid = N_ * B_ * 8 t-tiles = 1024 blocks = exactly 4 blocks/CU

static __device__ __forceinline__ float relu_log(float v) {
    v = fmaxf(v, 0.0f);
    return logf(v + 1e-5f);
}

// Fused: beamform magnitude (computed into LDS per f-chunk) + projection GEMM
// + relu + log + BN partial sums.
// Block: fixed (n, b, t-tile of 128). Threads 256: kx=tid&15 (5 k's each),
// ty=tid>>4 (8 t's each) -> thread tile 5k x 8t, block tile 80k x 128t.
__global__ __launch_bounds__(256, 4) void k_fused(
    const float* __restrict__ xr, const float* __restrict__ xi,
    const float* __restrict__ wr, const float* __restrict__ wi,
    const float* __restrict__ w_proj,
    float* __restrict__ out, double* __restrict__ sums) {

    const int tid = threadIdx.x;
    const int bid = blockIdx.x;
    const int b  = bid & 7;          // b fastest: sibling blocks share x chunk in L3
    const int tt = (bid >> 3) & 7;
    const int n  = bid >> 6;
    const int t0 = tt * TT_;

    __shared__ float magS[32][TT_];  // 16 KB: f-chunk x t-tile
    __shared__ float wS[32][TT_];    // 16 KB: f-chunk x (16 k-groups * 8 padded)

    const int kx = tid & 15;
    const int ty = tid >> 4;

    float acc[5][8];
#pragma unroll
    for (int j = 0; j < 5; ++j)
#pragma unroll
        for (int i = 0; i < 8; ++i) acc[j][i] = 0.f;

    const float* xrn = xr + (size_t)n * C_ * F_ * T_;
    const float* xin = xi + (size_t)n * C_ * F_ * T_;

    for (int ch = 0; ch < 8; ++ch) {
        const int f0 = ch * 32;
        // ---- stage w chunk: 80 k x 32 f, layout wS[f][kgroup*8 + j] ----
#pragma unroll
        for (int r = 0; r < 10; ++r) {
            int idx = tid + r * 256;           // 2560 = 80*32
            int k = idx >> 5, fc = idx & 31;
            wS[fc][(k / 5) * 8 + (k % 5)] = w_proj[k * F_ + f0 + fc];
        }
        // ---- compute mag chunk into LDS: 32 f x 128 t ----
#pragma unroll
        for (int r = 0; r < 4; ++r) {
            int idx = tid + r * 256;           // 1024 = 32*32
            int fr = idx >> 5, t4 = idx & 31;
            int f = f0 + fr;
            int tb = t0 + t4 * 4;
            if (tb < T_) {
                float xrv[C_][4], xiv[C_][4];
#pragma unroll
                for (int c = 0; c < C_; ++c) {
                    float4 vr = *(const float4*)(xrn + ((size_t)c * F_ + f) * T_ + tb);
                    float4 vi = *(const float4*)(xin + ((size_t)c * F_ + f) * T_ + tb);
                    xrv[c][0] = vr.x; xrv[c][1] = vr.y; xrv[c][2] = vr.z; xrv[c][3] = vr.w;
                    xiv[c][0] = vi.x; xiv[c][1] = vi.y; xiv[c][2] = vi.z; xiv[c][3] = vi.w;
                }
                float4 wrv = *(const float4*)(wr + (size_t)(f * B_ + b) * C_);
                float4 wiv = *(const float4*)(wi + (size_t)(f * B_ + b) * C_);
                float wrc[4] = {wrv.x, wrv.y, wrv.z, wrv.w};
                float wic[4] = {wiv.x, wiv.y, wiv.z, wiv.w};
                float4 mres;
                float* mp = &mres.x;
#pragma unroll
                for (int i = 0; i < 4; ++i) {
                    float br = 0.f, bim = 0.f;
#pragma unroll
                    for (int c = 0; c < C_; ++c) {
                        br  += xrv[c][i] * wrc[c] - xiv[c][i] * wic[c];
                        bim += xiv[c][i] * wrc[c] + xrv[c][i] * wic[c];
                    }
                    mp[i] = sqrtf(br * br + bim * bim + 1e-5f);
                }
                *(float4*)&magS[fr][t4 * 4] = mres;
            } else {
                *(float4*)&magS[fr][t4 * 4] = make_float4(0.f, 0.f, 0.f, 0.f);
            }
        }
        __syncthreads();
        // ---- GEMM over the 32 f rows ----
#pragma unroll 4
        for (int fc = 0; fc < 32; ++fc) {
            float4 m0 = *(const float4*)&magS[fc][ty * 8];
            float4 m1 = *(const float4*)&magS[fc][ty * 8 + 4];
            float4 w0 = *(const float4*)&wS[fc][kx * 8];
            float  w4 = wS[fc][kx * 8 + 4];
            float wj[5] = {w0.x, w0.y, w0.z, w0.w, w4};
            float mi[8] = {m0.x, m0.y, m0.z, m0.w, m1.x, m1.y, m1.z, m1.w};
#pragma unroll
            for (int j = 0; j < 5; ++j)
#pragma unroll
                for (int i = 0; i < 8; ++i)
                    acc[j][i] += wj[j] * mi[i];
        }
        __syncthreads();
    }

    // ---- tail f = 256 ----
    if (tid < 80)
        wS[0][(tid / 5) * 8 + (tid % 5)] = w_proj[tid * F_ + 256];
    if (tid >= 128 && tid < 160) {
        int t4 = tid - 128;
        int tb = t0 + t4 * 4;
        if (tb < T_) {
            float xrv[C_][4], xiv[C_][4];
#pragma unroll
            for (int c = 0; c < C_; ++c) {
                float4 vr = *(const float4*)(xrn + ((size_t)c * F_ + 256) * T_ + tb);
                float4 vi = *(const float4*)(xin + ((size_t)c * F_ + 256) * T_ + tb);
                xrv[c][0] = vr.x; xrv[c][1] = vr.y; xrv[c][2] = vr.z; xrv[c][3] = vr.w;
                xiv[c][0] = vi.x; xiv[c][1] = vi.y; xiv[c][2] = vi.z; xiv[c][3] = vi.w;
            }
            float4 wrv = *(const float4*)(wr + (size_t)(256 * B_ + b) * C_);
            float4 wiv = *(const float4*)(wi + (size_t)(256 * B_ + b) * C_);
            float wrc[4] = {wrv.x, wrv.y, wrv.z, wrv.w};
            float wic[4] = {wiv.x, wiv.y, wiv.z, wiv.w};
            float4 mres;
            float* mp = &mres.x;
#pragma unroll
            for (int i = 0; i < 4; ++i) {
                float br = 0.f, bim = 0.f;
#pragma unroll
                for (int c = 0; c < C_; ++c) {
                    br  += xrv[c][i] * wrc[c] - xiv[c][i] * wic[c];
                    bim += xiv[c][i] * wrc[c] + xrv[c][i] * wic[c];
                }
                mp[i] = sqrtf(br * br + bim * bim + 1e-5f);
            }
            *(float4*)&magS[0][t4 * 4] = mres;
        } else {
            *(float4*)&magS[0][t4 * 4] = make_float4(0.f, 0.f, 0.f, 0.f);
        }
    }
    __syncthreads();
    {
        float4 m0 = *(const float4*)&magS[0][ty * 8];
        float4 m1 = *(const float4*)&magS[0][ty * 8 + 4];
        float4 w0 = *(const float4*)&wS[0][kx * 8];
        float  w4 = wS[0][kx * 8 + 4];
        float wj[5] = {w0.x, w0.y, w0.z, w0.w, w4};
        float mi[8] = {m0.x, m0.y, m0.z, m0.w, m1.x, m1.y, m1.z, m1.w};
#pragma unroll
        for (int j = 0; j < 5; ++j)
#pragma unroll
            for (int i = 0; i < 8; ++i)
                acc[j][i] += wj[j] * mi[i];
    }

    // ---- epilogue: relu+log, store, BN partial sums ----
    double s1 = 0.0, s2 = 0.0;
#pragma unroll
    for (int i = 0; i < 8; ++i) {
        int t = t0 + ty * 8 + i;
        if (t < T_) {
            float* orow = out + ((size_t)n * T_ + t) * BK_ + b * K_ + kx * 5;
#pragma unroll
            for (int j = 0; j < 5; ++j) {
                float v = relu_log(acc[j][i]);
                orow[j] = v;
                s1 += (double)v;
                s2 += (double)v * (double)v;
            }
        }
    }
#pragma unroll
    for (int off = 32; off; off >>= 1) {
        s1 += __shfl_down(s1, off);
        s2 += __shfl_down(s2, off);
    }
    __shared__ double red1[4], red2[4];
    int wid = tid >> 6, lane = tid & 63;
    if (lane == 0) { red1[wid] = s1; red2[wid] = s2; }
    __syncthreads();
    if (tid == 0) {
        double a1 = red1[0] + red1[1] + red1[2] + red1[3];
        double a2 = red2[0] + red2[1] + red2[2] + red2[3];
        atomicAdd(&sums[b], a1);
        atomicAdd(&sums[B_ + b], a2);
    }
}

// ---------------- per-channel scale/shift from sums ----------------
__global__ void k_bnstats(const double* __restrict__ sums,
                          const float* __restrict__ gamma,
                          const float* __restrict__ beta,
                          float* __restrict__ ss) {
    int b = threadIdx.x;
    if (b < B_) {
        const double cnt = (double)N_ * T_ * K_;
        double mean = sums[b] / cnt;
        double var = sums[B_ + b] / cnt - mean * mean;
        float scale = gamma[b] * (float)(1.0 / sqrt(var + 1e-5));
        float shift = beta[b] - (float)mean * scale;
        ss[b] = scale;
        ss[B_ + b] = shift;
    }
}

// ---------------- apply BN in place over d_out ----------------
__global__ __launch_bounds__(256) void k_bnapply(float* __restrict__ out,
                                                 const float* __restrict__ ss) {
    size_t i4 = (size_t)blockIdx.x * 256 + threadIdx.x;
    int k4 = (int)(i4 % (BK_ / 4));  // 160 float4 per (n,t) row
    int b = k4 / (K_ / 4);           // 20 float4 per channel
    float scale = ss[b], shift = ss[B_ + b];
    float4* p = (float4*)out + i4;
    float4 v = *p;
    v.x = v.x * scale + shift;
    v.y = v.y * scale + shift;
    v.z = v.z * scale + shift;
    v.w = v.w * scale + shift;
    *p = v;
}

extern "C" void kernel_launch(void* const* d_in, const int* in_sizes, int n_in,
                              void* d_out, int out_size, void* d_ws, size_t ws_size,
                              hipStream_t stream) {
    const float* xr = (const float*)d_in[0];
    const float* xi = (const float*)d_in[1];
    const float* wr = (const float*)d_in[2];
    const float* wi = (const float*)d_in[3];
    const float* w_proj = (const float*)d_in[4];
    const float* gamma = (const float*)d_in[5];
    const float* beta = (const float*)d_in[6];
    float* out = (float*)d_out;

    double* sums = (double*)d_ws;             // 16 doubles
    float* ss = (float*)((char*)d_ws + 128);  // 16 floats

    hipMemsetAsync(d_ws, 0, 512, stream);
    k_fused<<<N_ * B_ * 8, 256, 0, stream>>>(xr, xi, wr, wi, w_proj, out, sums);
    k_bnstats<<<1, 64, 0, stream>>>(sums, gamma, beta, ss);
    k_bnapply<<<10000, 256, 0, stream>>>(out, ss);
}

// Round 4
// 168.801 us; speedup vs baseline: 1.1661x; 1.1661x over previous
//
#include <hip/hip_runtime.h>
#include <math.h>

#define N_ 16
#define C_ 4
#define F_ 257
#define T_ 1000
#define B_ 8
#define K_ 80
#define BK_ 640
#define TT_ 16
#define NT_ 63            // ceil(1000/16)
#define NBLK (N_ * NT_)   // 1008
#define MSTR 260          // magS row stride (floats)
#define WSTR 162          // wS row stride (floats); k-group stride 10

static __device__ __forceinline__ float relu_log(float v) {
    v = fmaxf(v, 0.0f);
    return logf(v + 1e-5f);
}

// One block = (n, 16-t tile), ALL 8 beams. x read exactly once globally.
// GEMM threads: kx=tid&15 (5 k's), ty=tid>>4 (1 t). Thread tile = 8b x 5k x 1t.
// Mag-stage roles: bh=tid&1 (4 b's), t4=(tid>>1)&3 (4 t's), fr=tid>>3 (f row).
__global__ __launch_bounds__(256, 3) void k_fused(
    const float* __restrict__ xr, const float* __restrict__ xi,
    const float* __restrict__ wr, const float* __restrict__ wi,
    const float* __restrict__ w_proj,
    float* __restrict__ out, double* __restrict__ partials) {

    const int tid = threadIdx.x;
    const int bid = blockIdx.x;
    const int tt = bid % NT_;
    const int n  = bid / NT_;
    const int t0 = tt * TT_;

    __shared__ float magS[TT_][MSTR];   // [t][f*8 + b]
    __shared__ float wS[32][WSTR];      // [f][(k/5)*10 + k%5]
    __shared__ double redS[2][4][B_];

    const int kx = tid & 15;
    const int ty = tid >> 4;

    const int m_bh = tid & 1;
    const int m_t4 = (tid >> 1) & 3;
    const int m_fr = tid >> 3;
    const int m_b0 = m_bh * 4;

    float acc[B_][5];
#pragma unroll
    for (int b = 0; b < B_; ++b)
#pragma unroll
        for (int j = 0; j < 5; ++j) acc[b][j] = 0.f;

    const float* xrn = xr + (size_t)n * C_ * F_ * T_;
    const float* xin = xi + (size_t)n * C_ * F_ * T_;
    const int kbase = tid >> 5;         // 0..7 (w staging)
    const int wfc   = tid & 31;

    for (int ch = 0; ch < 8; ++ch) {
        const int f0 = ch * 32;
        // ---- stage w chunk: 80k x 32f ----
#pragma unroll
        for (int r = 0; r < 10; ++r) {
            int k = kbase + 8 * r;
            wS[wfc][(k / 5) * 10 + (k % 5)] = w_proj[k * F_ + f0 + wfc];
        }
        // ---- beamform mag chunk into LDS: thread = (fr, t4, bh) ----
        {
            const int f  = f0 + m_fr;
            const int tb = t0 + m_t4 * 4;
            float m[4][4];  // [t][b]
            if (tb + 4 <= T_) {
                const float* xrp = xrn + (size_t)f * T_ + tb;
                const float* xip = xin + (size_t)f * T_ + tb;
                float xrv[C_][4], xiv[C_][4];
#pragma unroll
                for (int c = 0; c < C_; ++c) {
                    float4 vr = *(const float4*)(xrp + (size_t)c * F_ * T_);
                    float4 vi = *(const float4*)(xip + (size_t)c * F_ * T_);
                    xrv[c][0] = vr.x; xrv[c][1] = vr.y; xrv[c][2] = vr.z; xrv[c][3] = vr.w;
                    xiv[c][0] = vi.x; xiv[c][1] = vi.y; xiv[c][2] = vi.z; xiv[c][3] = vi.w;
                }
                const float* wrp = wr + (size_t)(f * B_ + m_b0) * C_;
                const float* wip = wi + (size_t)(f * B_ + m_b0) * C_;
#pragma unroll
                for (int jb = 0; jb < 4; ++jb) {
                    float4 wrv = *(const float4*)(wrp + jb * C_);
                    float4 wiv = *(const float4*)(wip + jb * C_);
                    float wrc[4] = {wrv.x, wrv.y, wrv.z, wrv.w};
                    float wic[4] = {wiv.x, wiv.y, wiv.z, wiv.w};
#pragma unroll
                    for (int i = 0; i < 4; ++i) {
                        float br = 0.f, bi2 = 0.f;
#pragma unroll
                        for (int c = 0; c < C_; ++c) {
                            br  += xrv[c][i] * wrc[c] - xiv[c][i] * wic[c];
                            bi2 += xiv[c][i] * wrc[c] + xrv[c][i] * wic[c];
                        }
                        m[i][jb] = sqrtf(br * br + bi2 * bi2 + 1e-5f);
                    }
                }
            } else {
#pragma unroll
                for (int i = 0; i < 4; ++i)
#pragma unroll
                    for (int jb = 0; jb < 4; ++jb) m[i][jb] = 0.f;
            }
#pragma unroll
            for (int i = 0; i < 4; ++i)
                *(float4*)&magS[m_t4 * 4 + i][m_fr * 8 + m_b0] =
                    make_float4(m[i][0], m[i][1], m[i][2], m[i][3]);
        }
        __syncthreads();
        // ---- GEMM over 32 f rows ----
#pragma unroll 8
        for (int fc = 0; fc < 32; ++fc) {
            float4 m0 = *(const float4*)&magS[ty][fc * 8];
            float4 m1 = *(const float4*)&magS[ty][fc * 8 + 4];
            float2 wa = *(const float2*)&wS[fc][kx * 10];      // 8B-aligned
            float2 wb = *(const float2*)&wS[fc][kx * 10 + 2];
            float  w4 = wS[fc][kx * 10 + 4];
            float wj[5] = {wa.x, wa.y, wb.x, wb.y, w4};
            float mb[8] = {m0.x, m0.y, m0.z, m0.w, m1.x, m1.y, m1.z, m1.w};
#pragma unroll
            for (int b = 0; b < B_; ++b)
#pragma unroll
                for (int j = 0; j < 5; ++j)
                    acc[b][j] += mb[b] * wj[j];
        }
        __syncthreads();
    }

    // ---- tail f = 256 ----
    if (tid < 80)
        wS[0][(tid / 5) * 10 + (tid % 5)] = w_proj[tid * F_ + 256];
    if (tid >= 128) {
        int id = tid - 128;
        int trow = id >> 3;
        int b = id & 7;
        int t = t0 + trow;
        float v = 0.f;
        if (t < T_) {
            const float* wrp = wr + (size_t)(256 * B_ + b) * C_;
            const float* wip = wi + (size_t)(256 * B_ + b) * C_;
            float br = 0.f, bi2 = 0.f;
#pragma unroll
            for (int c = 0; c < C_; ++c) {
                float xrv = xrn[((size_t)c * F_ + 256) * T_ + t];
                float xiv = xin[((size_t)c * F_ + 256) * T_ + t];
                br  += xrv * wrp[c] - xiv * wip[c];
                bi2 += xiv * wrp[c] + xrv * wip[c];
            }
            v = sqrtf(br * br + bi2 * bi2 + 1e-5f);
        }
        magS[trow][b] = v;
    }
    __syncthreads();
    {
        float4 m0 = *(const float4*)&magS[ty][0];
        float4 m1 = *(const float4*)&magS[ty][4];
        float2 wa = *(const float2*)&wS[0][kx * 10];
        float2 wb = *(const float2*)&wS[0][kx * 10 + 2];
        float  w4 = wS[0][kx * 10 + 4];
        float wj[5] = {wa.x, wa.y, wb.x, wb.y, w4};
        float mb[8] = {m0.x, m0.y, m0.z, m0.w, m1.x, m1.y, m1.z, m1.w};
#pragma unroll
        for (int b = 0; b < B_; ++b)
#pragma unroll
            for (int j = 0; j < 5; ++j)
                acc[b][j] += mb[b] * wj[j];
    }

    // ---- epilogue: relu+log, store, per-b BN partial sums ----
    float s1f[B_], s2f[B_];
#pragma unroll
    for (int b = 0; b < B_; ++b) { s1f[b] = 0.f; s2f[b] = 0.f; }
    const int t = t0 + ty;
    if (t < T_) {
        float* orow = out + ((size_t)n * T_ + t) * BK_ + kx * 5;
#pragma unroll
        for (int b = 0; b < B_; ++b) {
#pragma unroll
            for (int j = 0; j < 5; ++j) {
                float v = relu_log(acc[b][j]);
                orow[b * K_ + j] = v;
                s1f[b] += v;
                s2f[b] += v * v;
            }
        }
    }
    const int wid = tid >> 6, lane = tid & 63;
#pragma unroll
    for (int b = 0; b < B_; ++b) {
        double d1 = (double)s1f[b], d2 = (double)s2f[b];
#pragma unroll
        for (int off = 32; off; off >>= 1) {
            d1 += __shfl_down(d1, off);
            d2 += __shfl_down(d2, off);
        }
        if (lane == 0) { redS[0][wid][b] = d1; redS[1][wid][b] = d2; }
    }
    __syncthreads();
    // plain deterministic per-block partial stores (no atomics, no memset dep)
    if (tid < 8) {
        partials[(size_t)bid * 16 + tid] =
            redS[0][0][tid] + redS[0][1][tid] + redS[0][2][tid] + redS[0][3][tid];
    } else if (tid >= 64 && tid < 72) {
        int b = tid - 64;
        partials[(size_t)bid * 16 + 8 + b] =
            redS[1][0][b] + redS[1][1][b] + redS[1][2][b] + redS[1][3][b];
    }
}

// ---------------- reduce partials -> per-channel scale/shift ----------------
// 256 threads: tid = b*32 + i; each (b,i) strides the 1008 blocks.
__global__ __launch_bounds__(256) void k_bnstats(
    const double* __restrict__ partials,
    const float* __restrict__ gamma, const float* __restrict__ beta,
    float* __restrict__ ss) {
    const int b = threadIdx.x >> 5;
    const int i = threadIdx.x & 31;
    double s1 = 0.0, s2 = 0.0;
    for (int j = i; j < NBLK; j += 32) {
        s1 += partials[(size_t)j * 16 + b];
        s2 += partials[(size_t)j * 16 + 8 + b];
    }
#pragma unroll
    for (int off = 16; off; off >>= 1) {
        s1 += __shfl_down(s1, off);
        s2 += __shfl_down(s2, off);
    }
    if (i == 0) {
        const double cnt = (double)N_ * T_ * K_;
        double mean = s1 / cnt;
        double var = s2 / cnt - mean * mean;
        float scale = gamma[b] * (float)(1.0 / sqrt(var + 1e-5));
        float shift = beta[b] - (float)mean * scale;
        ss[b] = scale;
        ss[B_ + b] = shift;
    }
}

// ---------------- apply BN in place over d_out ----------------
__global__ __launch_bounds__(256) void k_bnapply(float* __restrict__ out,
                                                 const float* __restrict__ ss) {
    size_t i4 = (size_t)blockIdx.x * 256 + threadIdx.x;
    int k4 = (int)(i4 % (BK_ / 4));
    int b = k4 / (K_ / 4);
    float scale = ss[b], shift = ss[B_ + b];
    float4* p = (float4*)out + i4;
    float4 v = *p;
    v.x = v.x * scale + shift;
    v.y = v.y * scale + shift;
    v.z = v.z * scale + shift;
    v.w = v.w * scale + shift;
    *p = v;
}

extern "C" void kernel_launch(void* const* d_in, const int* in_sizes, int n_in,
                              void* d_out, int out_size, void* d_ws, size_t ws_size,
                              hipStream_t stream) {
    const float* xr = (const float*)d_in[0];
    const float* xi = (const float*)d_in[1];
    const float* wr = (const float*)d_in[2];
    const float* wi = (const float*)d_in[3];
    const float* w_proj = (const float*)d_in[4];
    const float* gamma = (const float*)d_in[5];
    const float* beta = (const float*)d_in[6];
    float* out = (float*)d_out;

    double* partials = (double*)d_ws;                       // 1008*16 doubles
    float* ss = (float*)((char*)d_ws + NBLK * 16 * 8 + 64); // 16 floats

    k_fused<<<NBLK, 256, 0, stream>>>(xr, xi, wr, wi, w_proj, out, partials);
    k_bnstats<<<1, 256, 0, stream>>>(partials, gamma, beta, ss);
    k_bnapply<<<10000, 256, 0, stream>>>(out, ss);
}